// Round 1
// baseline (429.614 us; speedup 1.0000x reference)
//
#include <hip/hip_runtime.h>
#include <hip/hip_bf16.h>

// SparseGather: inputs (N=4,H=512,W=512,C=64) f32, M=4096 active blocks of
// 16x16 spatial extent (stride 16, offset 0). out[m,i,j,c] = in[n, y0+i, x0+j, c].
// Per (m,i): 16*64 = 1024 contiguous floats (4 KiB) -> one float4 per thread
// with 256 threads. 16 rows per block.

__global__ __launch_bounds__(256) void sparse_gather_kernel(
    const float* __restrict__ in,
    const int* __restrict__ idx,
    float* __restrict__ out,
    int M)
{
    const int m = blockIdx.x;
    if (m >= M) return;
    const int t = threadIdx.x;

    const int n  = idx[m * 3 + 0];
    const int by = idx[m * 3 + 1];
    const int bx = idx[m * 3 + 2];

    // NHWC: base element offset of (n, by*16, bx*16, 0)
    const long long H = 512, W = 512, C = 64;
    const long long y0 = (long long)by * 16;
    const long long x0 = (long long)bx * 16;
    const long long base = (((long long)n * H + y0) * W + x0) * C;

    const float4* __restrict__ src = reinterpret_cast<const float4*>(in + base);
    float4* __restrict__ dst = reinterpret_cast<float4*>(out + (long long)m * (16 * 16 * 64));

    // Row stride in float4 units: W*C/4 = 8192. Per row: 1024 floats = 256 float4.
#pragma unroll
    for (int i = 0; i < 16; ++i) {
        dst[i * 256 + t] = src[(long long)i * 8192 + t];
    }
}

extern "C" void kernel_launch(void* const* d_in, const int* in_sizes, int n_in,
                              void* d_out, int out_size, void* d_ws, size_t ws_size,
                              hipStream_t stream) {
    const float* in  = (const float*)d_in[0];
    // d_in[1] = bin_counts (unused; M is static per in_sizes)
    const int* idx   = (const int*)d_in[2];
    float* out       = (float*)d_out;

    const int M = in_sizes[2] / 3;  // 4096

    sparse_gather_kernel<<<dim3(M), dim3(256), 0, stream>>>(in, idx, out, M);
}